// Round 1
// baseline (561.236 us; speedup 1.0000x reference)
//
#include <hip/hip_runtime.h>

#define EPS 1e-5f

typedef __attribute__((ext_vector_type(8))) short short8;
typedef __attribute__((ext_vector_type(4))) float f32x4;
typedef __attribute__((ext_vector_type(2))) float f32x2;

// ---- ws layout ----
// bf16 region (ushort):
//   [0, 131072)           : shW in frag-slab layout ((k>>3)*256 + n)*8 + (k&7), BN0 scale folded
//   [131072, 180224)      : stW[s] (s=0..2) frag layout, only live cols n'∈[0,128) where
//                           n = n' (<64) or n'+64 (>=64); idx per s: ((k>>3)*128 + n')*8 + (k&7)
// float region (float*, offsets in floats):
//   90112: c1[256]   90368: c2[256]   90624: stc1[3][256]   91392: stc2[3][256]
#define C1_OFF   90112
#define C2_OFF   90368
#define STC1_OFF 90624
#define STC2_OFF 91392

__device__ inline unsigned short f2bf(float f) {
  unsigned u = __builtin_bit_cast(unsigned, f);
  u += 0x7FFFu + ((u >> 16) & 1u);
  return (unsigned short)(u >> 16);
}
__device__ inline float bf2f(unsigned short h) {
  unsigned u = ((unsigned)h) << 16;
  return __builtin_bit_cast(float, u);
}

__device__ inline void gl_lds16(const void* g, void* l) {
  __builtin_amdgcn_global_load_lds(
      (__attribute__((address_space(1))) void*)(g),
      (__attribute__((address_space(3))) void*)(l), 16, 0, 0);
}

// ---------------- prep kernels ----------------
__global__ void prep_w(const float* __restrict__ shW, const float* __restrict__ stW,
                       const float* __restrict__ bn0_g, const float* __restrict__ bn0_v,
                       unsigned short* __restrict__ ws) {
  int idx = blockIdx.x * 256 + threadIdx.x;
  if (idx < 131072) {
    int j = idx & 7, t = idx >> 3;
    int n = t & 255, kq = t >> 8;
    int k = kq * 8 + j;
    float scale = bn0_g[k] * rsqrtf(bn0_v[k] + EPS);
    ws[idx] = f2bf(shW[k * 256 + n] * scale);
  } else if (idx < 131072 + 49152) {
    int r = idx - 131072;
    int s = r >> 14;
    int rr = r & 16383;
    int j = rr & 7, t = rr >> 3;
    int np = t & 127, kq = t >> 7;
    int k = kq * 8 + j;
    int n = np < 64 ? np : np + 64;
    ws[idx] = f2bf(stW[(s * 128 + k) * 256 + n]);
  }
}

__global__ void prep_v(const float* __restrict__ shW,
                       const float* __restrict__ bn0_g, const float* __restrict__ bn0_b,
                       const float* __restrict__ bn0_m, const float* __restrict__ bn0_v,
                       const float* __restrict__ sh_g, const float* __restrict__ sh_b,
                       const float* __restrict__ sh_m, const float* __restrict__ sh_v,
                       const float* __restrict__ st_g, const float* __restrict__ st_b,
                       const float* __restrict__ st_m, const float* __restrict__ st_v,
                       float* __restrict__ wsf) {
  int n = threadIdx.x;  // 0..255
  float bias = 0.f;
  for (int k = 0; k < 512; ++k) {
    float sc = bn0_g[k] * rsqrtf(bn0_v[k] + EPS);
    float s0 = bn0_b[k] - bn0_m[k] * sc;
    bias += s0 * shW[k * 256 + n];
  }
  float c1 = sh_g[n] * rsqrtf(sh_v[n] + EPS);
  wsf[C1_OFF + n] = c1;
  wsf[C2_OFF + n] = (bias - sh_m[n]) * c1 + sh_b[n];
  for (int s = 0; s < 3; ++s) {
    float a = st_g[s * 256 + n] * rsqrtf(st_v[s * 256 + n] + EPS);
    wsf[STC1_OFF + s * 256 + n] = a;
    wsf[STC2_OFF + s * 256 + n] = st_b[s * 256 + n] - st_m[s * 256 + n] * a;
  }
}

// ---------------- main fused kernel ----------------
// grid = 2048 blocks x 256 threads; each block does 64 rows end-to-end.
__global__ __launch_bounds__(256) void tabnet_main(
    const float* __restrict__ x, const unsigned short* __restrict__ wsu,
    const float* __restrict__ wsf, const float* __restrict__ fW,
    const float* __restrict__ fb, float* __restrict__ out) {

  // stage buffer (32KB = 16384 ushort) aliased with raw buffer (64 rows * stride 264)
  __shared__ __align__(16) unsigned short lds_stage[64 * 264];  // 33792 B
  __shared__ __align__(16) unsigned short lds_sh[16 * 64 * 8];  // 16384 B
  unsigned short* lds_raw = lds_stage;

  const int tid = threadIdx.x;
  const int wave = tid >> 6, lane = tid & 63;
  const int q = lane >> 4, l15 = lane & 15;
  const long row0 = (long)blockIdx.x * 64;

  f32x4 acc[4][4];
#pragma unroll
  for (int a = 0; a < 4; ++a)
#pragma unroll
    for (int b = 0; b < 4; ++b) acc[a][b] = (f32x4)0.f;

  // ---- Phase 1: raw1 = bf16(x) @ shW'  (K=512, N=256, wave owns 64 cols) ----
  for (int ch = 0; ch < 8; ++ch) {
    __syncthreads();  // previous chunk's LDS reads complete
    {
      const unsigned char* src =
          (const unsigned char*)wsu + ch * 32768 + wave * 8192 + lane * 16;
      unsigned char* dst = (unsigned char*)lds_stage + wave * 8192;
#pragma unroll
      for (int i = 0; i < 8; ++i) gl_lds16(src + i * 1024, dst + i * 1024);
    }
    __syncthreads();  // staging complete (vmcnt drained by barrier)
#pragma unroll
    for (int h = 0; h < 2; ++h) {
      const int kbase = ch * 64 + h * 32 + q * 8;
      short8 af[4];
#pragma unroll
      for (int mt = 0; mt < 4; ++mt) {
        const float* xp = x + (row0 + 16 * mt + l15) * 512 + kbase;
        f32x4 v0 = *(const f32x4*)xp;
        f32x4 v1 = *(const f32x4*)(xp + 4);
        short8 a;
        a[0] = (short)f2bf(v0[0]); a[1] = (short)f2bf(v0[1]);
        a[2] = (short)f2bf(v0[2]); a[3] = (short)f2bf(v0[3]);
        a[4] = (short)f2bf(v1[0]); a[5] = (short)f2bf(v1[1]);
        a[6] = (short)f2bf(v1[2]); a[7] = (short)f2bf(v1[3]);
        af[mt] = a;
      }
#pragma unroll
      for (int nt = 0; nt < 4; ++nt) {
        const int n = wave * 64 + nt * 16 + l15;
        short8 bf = *(const short8*)&lds_stage[(((h * 4 + q) << 8) + n) * 8];
#pragma unroll
        for (int mt = 0; mt < 4; ++mt)
          acc[mt][nt] =
              __builtin_amdgcn_mfma_f32_16x16x32_bf16(af[mt], bf, acc[mt][nt], 0, 0, 0);
      }
    }
  }
  __syncthreads();  // all stage reads done -> safe to overwrite as raw
  // epilogue 1: y = acc*c1[col]+c2[col] -> lds_raw (bf16, row stride 264)
#pragma unroll
  for (int nt = 0; nt < 4; ++nt) {
    const int col = wave * 64 + nt * 16 + l15;
    const float c1 = wsf[C1_OFF + col], c2 = wsf[C2_OFF + col];
#pragma unroll
    for (int mt = 0; mt < 4; ++mt)
#pragma unroll
      for (int r = 0; r < 4; ++r) {
        const int rl = 16 * mt + q * 4 + r;
        lds_raw[rl * 264 + col] = f2bf(acc[mt][nt][r] * c1 + c2);
      }
  }
  __syncthreads();
  // GLU-1 -> lds_sh in A-frag layout: ((c>>3)*64 + row)*8 + (c&7)
  {
    const int r = tid >> 2, c0 = (tid & 3) * 32;
#pragma unroll
    for (int m = 0; m < 4; ++m) {
      const int cb = c0 + m * 8;
      short8 w;
#pragma unroll
      for (int j = 0; j < 8; ++j) {
        float y1 = bf2f(lds_raw[r * 264 + cb + j]);
        float y2 = bf2f(lds_raw[r * 264 + 128 + cb + j]);
        w[j] = (short)f2bf(y1 / (1.f + __expf(-y2)));
      }
      *(short8*)&lds_sh[((cb >> 3) * 64 + r) * 8] = w;
    }
  }

  float agg[16];
#pragma unroll
  for (int i = 0; i < 16; ++i) agg[i] = 0.f;

  // ---- Phase 2: 3 steps, K=128, live cols n'∈[0,128) (h_a half is dead code) ----
  for (int s = 0; s < 3; ++s) {
    __syncthreads();  // GLU reads of raw / prev stage reads complete
    {
      const unsigned char* src = (const unsigned char*)(wsu + 131072) + s * 32768 +
                                 wave * 8192 + lane * 16;
      unsigned char* dst = (unsigned char*)lds_stage + wave * 8192;
#pragma unroll
      for (int i = 0; i < 8; ++i) gl_lds16(src + i * 1024, dst + i * 1024);
    }
    __syncthreads();
    f32x4 acc2[4][2];
#pragma unroll
    for (int a = 0; a < 4; ++a)
#pragma unroll
      for (int b = 0; b < 2; ++b) acc2[a][b] = (f32x4)0.f;
#pragma unroll
    for (int ks = 0; ks < 4; ++ks) {
      const int kq = ks * 4 + q;
      short8 af[4];
#pragma unroll
      for (int mt = 0; mt < 4; ++mt)
        af[mt] = *(const short8*)&lds_sh[(kq * 64 + 16 * mt + l15) * 8];
#pragma unroll
      for (int nt = 0; nt < 2; ++nt) {
        const int np = wave * 32 + nt * 16 + l15;
        short8 bf = *(const short8*)&lds_stage[(kq * 128 + np) * 8];
#pragma unroll
        for (int mt = 0; mt < 4; ++mt)
          acc2[mt][nt] =
              __builtin_amdgcn_mfma_f32_16x16x32_bf16(af[mt], bf, acc2[mt][nt], 0, 0, 0);
      }
    }
    __syncthreads();  // stage reads done -> overwrite as raw
#pragma unroll
    for (int nt = 0; nt < 2; ++nt) {
      const int cp = wave * 32 + nt * 16 + l15;  // col' in [0,128)
      const int n = cp < 64 ? cp : cp + 64;      // actual col in [0,64)∪[128,192)
      const float a1 = wsf[STC1_OFF + s * 256 + n], a2 = wsf[STC2_OFF + s * 256 + n];
#pragma unroll
      for (int mt = 0; mt < 4; ++mt)
#pragma unroll
        for (int r = 0; r < 4; ++r) {
          const int rl = 16 * mt + q * 4 + r;
          lds_raw[rl * 264 + cp] = f2bf(acc2[mt][nt][r] * a1 + a2);
        }
    }
    __syncthreads();
    {
      const int r = tid >> 2, c0 = (tid & 3) * 16;
#pragma unroll
      for (int j = 0; j < 16; ++j) {
        float y1 = bf2f(lds_raw[r * 264 + c0 + j]);
        float y2 = bf2f(lds_raw[r * 264 + 64 + c0 + j]);
        agg[j] += y1 / (1.f + __expf(-y2));
      }
    }
  }

  // ---- final: out = agg @ fW + fb ----
  {
    const int r = tid >> 2, c0 = (tid & 3) * 16;
    float p0 = 0.f, p1 = 0.f;
#pragma unroll
    for (int j = 0; j < 16; ++j) {
      float w0 = fW[(c0 + j) * 2], w1 = fW[(c0 + j) * 2 + 1];
      p0 += agg[j] * w0;
      p1 += agg[j] * w1;
    }
    p0 += __shfl_xor(p0, 1); p0 += __shfl_xor(p0, 2);
    p1 += __shfl_xor(p1, 1); p1 += __shfl_xor(p1, 2);
    if ((tid & 3) == 0) {
      f32x2 o;
      o[0] = p0 + fb[0];
      o[1] = p1 + fb[1];
      *(f32x2*)&out[(row0 + r) * 2] = o;
    }
  }
}

extern "C" void kernel_launch(void* const* d_in, const int* in_sizes, int n_in,
                              void* d_out, int out_size, void* d_ws, size_t ws_size,
                              hipStream_t stream) {
  const float* x     = (const float*)d_in[0];
  const float* bn0_g = (const float*)d_in[1];
  const float* bn0_b = (const float*)d_in[2];
  const float* bn0_m = (const float*)d_in[3];
  const float* bn0_v = (const float*)d_in[4];
  const float* shW   = (const float*)d_in[5];
  const float* sh_g  = (const float*)d_in[6];
  const float* sh_b  = (const float*)d_in[7];
  const float* sh_m  = (const float*)d_in[8];
  const float* sh_v  = (const float*)d_in[9];
  const float* stW   = (const float*)d_in[10];
  const float* st_g  = (const float*)d_in[11];
  const float* st_b  = (const float*)d_in[12];
  const float* st_m  = (const float*)d_in[13];
  const float* st_v  = (const float*)d_in[14];
  // d_in[15..19] = atW, at_g, at_b, at_m, at_v : dead code, unused
  const float* fW    = (const float*)d_in[20];
  const float* fb    = (const float*)d_in[21];

  unsigned short* wsu = (unsigned short*)d_ws;
  float* wsf = (float*)d_ws;

  prep_w<<<704, 256, 0, stream>>>(shW, stW, bn0_g, bn0_v, wsu);
  prep_v<<<1, 256, 0, stream>>>(shW, bn0_g, bn0_b, bn0_m, bn0_v, sh_g, sh_b, sh_m,
                                sh_v, st_g, st_b, st_m, st_v, wsf);
  tabnet_main<<<2048, 256, 0, stream>>>(x, wsu, wsf, fW, fb, (float*)d_out);
}

// Round 3
// 484.326 us; speedup vs baseline: 1.1588x; 1.1588x over previous
//
#include <hip/hip_runtime.h>

#define EPS 1e-5f

typedef __attribute__((ext_vector_type(8))) short short8;
typedef __attribute__((ext_vector_type(4))) float f32x4;

// ---- ws layout ----
// shorts [0, 131072)      : shW frags, idx = (kq*256 + n)*8 + j, k = kq*8+j (BN0 scale folded)
// shorts [131072, 180224) : stW frags, idx = 131072 + s*16384 + (kq*128 + n')*8 + j,
//                           n = n' (<64) or n'+64
// floats (on d_ws as float*):
#define C1_OFF   90112
#define C2_OFF   90368
#define STC1_OFF 90624
#define STC2_OFF 91392

__device__ inline unsigned short f2bf(float f) {
  unsigned u = __builtin_bit_cast(unsigned, f);
  u += 0x7FFFu + ((u >> 16) & 1u);
  return (unsigned short)(u >> 16);
}

__device__ inline short8 cvt8(f32x4 a, f32x4 b) {
  short8 r;
  r[0] = (short)f2bf(a[0]); r[1] = (short)f2bf(a[1]);
  r[2] = (short)f2bf(a[2]); r[3] = (short)f2bf(a[3]);
  r[4] = (short)f2bf(b[0]); r[5] = (short)f2bf(b[1]);
  r[6] = (short)f2bf(b[2]); r[7] = (short)f2bf(b[3]);
  return r;
}

// ---------------- prep kernels ----------------
// 88 blocks x 256: coalesced reads (lanes sweep n), 16B frag writes.
__global__ void prep_w(const float* __restrict__ shW, const float* __restrict__ stW,
                       const float* __restrict__ bn0_g, const float* __restrict__ bn0_v,
                       unsigned short* __restrict__ ws) {
  int t = blockIdx.x * 256 + threadIdx.x;
  if (t < 16384) {
    int kq = t >> 8, n = t & 255;
    short8 o;
#pragma unroll
    for (int j = 0; j < 8; ++j) {
      int k = kq * 8 + j;
      float scale = bn0_g[k] * rsqrtf(bn0_v[k] + EPS);
      o[j] = (short)f2bf(shW[k * 256 + n] * scale);
    }
    *(short8*)&ws[t * 8] = o;
  } else if (t < 16384 + 6144) {
    int r = t - 16384;
    int s = r >> 11, rem = r & 2047;
    int kq = rem >> 7, np = rem & 127;
    int n = np < 64 ? np : np + 64;
    short8 o;
#pragma unroll
    for (int j = 0; j < 8; ++j) o[j] = (short)f2bf(stW[(s * 128 + kq * 8 + j) * 256 + n]);
    *(short8*)&ws[131072 + r * 8] = o;
  }
}

// 256 blocks (one per output col n): parallel reduction for the folded BN0 bias.
__global__ void prep_b(const float* __restrict__ shW,
                       const float* __restrict__ bn0_g, const float* __restrict__ bn0_b,
                       const float* __restrict__ bn0_m, const float* __restrict__ bn0_v,
                       const float* __restrict__ sh_g, const float* __restrict__ sh_b,
                       const float* __restrict__ sh_m, const float* __restrict__ sh_v,
                       const float* __restrict__ st_g, const float* __restrict__ st_b,
                       const float* __restrict__ st_m, const float* __restrict__ st_v,
                       float* __restrict__ wsf) {
  const int n = blockIdx.x, t = threadIdx.x;
  float part = 0.f;
#pragma unroll
  for (int kk = 0; kk < 2; ++kk) {
    int k = t + kk * 256;
    float sc = bn0_g[k] * rsqrtf(bn0_v[k] + EPS);
    part += (bn0_b[k] - bn0_m[k] * sc) * shW[k * 256 + n];
  }
#pragma unroll
  for (int m = 1; m < 64; m <<= 1) part += __shfl_xor(part, m);
  __shared__ float wsum[4];
  if ((t & 63) == 0) wsum[t >> 6] = part;
  __syncthreads();
  if (t == 0) {
    float bias = wsum[0] + wsum[1] + wsum[2] + wsum[3];
    float c1 = sh_g[n] * rsqrtf(sh_v[n] + EPS);
    wsf[C1_OFF + n] = c1;
    wsf[C2_OFF + n] = (bias - sh_m[n]) * c1 + sh_b[n];
#pragma unroll
    for (int s = 0; s < 3; ++s) {
      float a = st_g[s * 256 + n] * rsqrtf(st_v[s * 256 + n] + EPS);
      wsf[STC1_OFF + s * 256 + n] = a;
      wsf[STC2_OFF + s * 256 + n] = st_b[s * 256 + n] - st_m[s * 256 + n] * a;
    }
  }
}

// ---------------- main fused kernel ----------------
// 2048 blocks x 256 threads, 64 rows/block. No LDS weight staging; B-frags load
// straight from ws (frag order -> coalesced dwordx4). Wave w owns value cols
// [w*32,w*32+32) AND gate cols +128 -> GLU fully in registers. Only 2 barriers.
__global__ __launch_bounds__(256) void tabnet_main(
    const float* __restrict__ x, const unsigned short* __restrict__ wsu,
    const float* __restrict__ wsf, const float* __restrict__ fW,
    const float* __restrict__ fb, float* __restrict__ out) {

  __shared__ __align__(16) unsigned short lds_sh[16 * 64 * 8];  // 16 KB, sh A-frags
  __shared__ float lds_red[4 * 64 * 2];                         // 2 KB

  const int tid = threadIdx.x;
  const int wave = tid >> 6, lane = tid & 63;
  const int q = lane >> 4, l15 = lane & 15;
  const long row0 = (long)blockIdx.x * 64;

  // B column per nt: nt 0,1 = value cols, nt 2,3 = gate cols (+128)
  int ncol[4];
#pragma unroll
  for (int nt = 0; nt < 4; ++nt)
    ncol[nt] = wave * 32 + (nt & 1) * 16 + (nt >> 1) * 128 + l15;

  const float* xrow = x + (row0 + l15) * 512 + q * 8;

  f32x4 acc[4][4];
#pragma unroll
  for (int a = 0; a < 4; ++a)
#pragma unroll
    for (int b = 0; b < 4; ++b) acc[a][b] = (f32x4)0.f;

  // ---- Phase 1: K=512 as 16 steps of 32; x pipelined 1 step ahead ----
  f32x4 xa[4], xb[4];
#pragma unroll
  for (int mt = 0; mt < 4; ++mt) {
    const float* p = xrow + mt * 8192;
    xa[mt] = *(const f32x4*)p;
    xb[mt] = *(const f32x4*)(p + 4);
  }
  for (int st = 0; st < 16; ++st) {
    // issue B loads for this step (latency hidden behind the x wait below)
    short8 bcur[4];
#pragma unroll
    for (int nt = 0; nt < 4; ++nt)
      bcur[nt] = *(const short8*)&wsu[((st * 4 + q) * 256 + ncol[nt]) * 8];
    // convert current x (waits on x loads issued last step)
    short8 af[4];
#pragma unroll
    for (int mt = 0; mt < 4; ++mt) af[mt] = cvt8(xa[mt], xb[mt]);
    // prefetch next step's x
    if (st < 15) {
#pragma unroll
      for (int mt = 0; mt < 4; ++mt) {
        const float* p = xrow + mt * 8192 + (st + 1) * 32;
        xa[mt] = *(const f32x4*)p;
        xb[mt] = *(const f32x4*)(p + 4);
      }
    }
#pragma unroll
    for (int nt = 0; nt < 4; ++nt)
#pragma unroll
      for (int mt = 0; mt < 4; ++mt)
        acc[mt][nt] =
            __builtin_amdgcn_mfma_f32_16x16x32_bf16(af[mt], bcur[nt], acc[mt][nt], 0, 0, 0);
  }

  // ---- Phase-1 epilogue: BN + GLU in registers -> lds_sh (A-frag layout) ----
#pragma unroll
  for (int nt = 0; nt < 2; ++nt) {
    const int c = wave * 32 + nt * 16 + l15;
    const float v1 = wsf[C1_OFF + c], v2 = wsf[C2_OFF + c];
    const float g1 = wsf[C1_OFF + c + 128], g2 = wsf[C2_OFF + c + 128];
#pragma unroll
    for (int mt = 0; mt < 4; ++mt)
#pragma unroll
      for (int r = 0; r < 4; ++r) {
        float y1 = acc[mt][nt][r] * v1 + v2;
        float y2 = acc[mt][nt + 2][r] * g1 + g2;
        float sg = __builtin_amdgcn_rcpf(1.f + __expf(-y2));
        int row = 16 * mt + 4 * q + r;
        lds_sh[((c >> 3) * 64 + row) * 8 + (c & 7)] = f2bf(y1 * sg);
      }
  }
  __syncthreads();

  // ---- Phase 2: 3 steps, K=128; A from lds_sh, B direct from global; GLU in regs ----
  float agg[16];
#pragma unroll
  for (int i = 0; i < 16; ++i) agg[i] = 0.f;

  for (int s = 0; s < 3; ++s) {
    const unsigned short* wb = wsu + 131072 + s * 16384;
    short8 bs[4][2];
#pragma unroll
    for (int ks = 0; ks < 4; ++ks) {
      int kq = ks * 4 + q;
      bs[ks][0] = *(const short8*)&wb[(kq * 128 + wave * 16 + l15) * 8];
      bs[ks][1] = *(const short8*)&wb[(kq * 128 + 64 + wave * 16 + l15) * 8];
    }
    f32x4 acc2[4][2];
#pragma unroll
    for (int a = 0; a < 4; ++a)
#pragma unroll
      for (int b = 0; b < 2; ++b) acc2[a][b] = (f32x4)0.f;
#pragma unroll
    for (int ks = 0; ks < 4; ++ks) {
      int kq = ks * 4 + q;
      short8 af[4];
#pragma unroll
      for (int mt = 0; mt < 4; ++mt)
        af[mt] = *(const short8*)&lds_sh[(kq * 64 + 16 * mt + l15) * 8];
#pragma unroll
      for (int nt = 0; nt < 2; ++nt)
#pragma unroll
        for (int mt = 0; mt < 4; ++mt)
          acc2[mt][nt] =
              __builtin_amdgcn_mfma_f32_16x16x32_bf16(af[mt], bs[ks][nt], acc2[mt][nt], 0, 0, 0);
    }
    const int n1 = wave * 16 + l15, n2 = 128 + wave * 16 + l15;
    const float a1 = wsf[STC1_OFF + s * 256 + n1], b1 = wsf[STC2_OFF + s * 256 + n1];
    const float a2 = wsf[STC1_OFF + s * 256 + n2], b2 = wsf[STC2_OFF + s * 256 + n2];
#pragma unroll
    for (int mt = 0; mt < 4; ++mt)
#pragma unroll
      for (int r = 0; r < 4; ++r) {
        float y1 = acc2[mt][0][r] * a1 + b1;
        float y2 = acc2[mt][1][r] * a2 + b2;
        agg[mt * 4 + r] += y1 * __builtin_amdgcn_rcpf(1.f + __expf(-y2));
      }
  }

  // ---- Final: out = agg @ fW + fb (shfl reduce over the 16 cols per wave) ----
  {
    const int c = wave * 16 + l15;
    const float w0 = fW[c * 2], w1 = fW[c * 2 + 1];
#pragma unroll
    for (int mt = 0; mt < 4; ++mt)
#pragma unroll
      for (int r = 0; r < 4; ++r) {
        float p0 = agg[mt * 4 + r] * w0;
        float p1 = agg[mt * 4 + r] * w1;
#pragma unroll
        for (int m = 1; m < 16; m <<= 1) {
          p0 += __shfl_xor(p0, m);
          p1 += __shfl_xor(p1, m);
        }
        if (l15 == 0) {
          int row = 16 * mt + 4 * q + r;
          lds_red[(wave * 64 + row) * 2] = p0;
          lds_red[(wave * 64 + row) * 2 + 1] = p1;
        }
      }
  }
  __syncthreads();
  if (tid < 128) {
    int row = tid >> 1, o = tid & 1;
    float v = fb[o];
#pragma unroll
    for (int w = 0; w < 4; ++w) v += lds_red[(w * 64 + row) * 2 + o];
    out[(row0 + row) * 2 + o] = v;
  }
}

extern "C" void kernel_launch(void* const* d_in, const int* in_sizes, int n_in,
                              void* d_out, int out_size, void* d_ws, size_t ws_size,
                              hipStream_t stream) {
  const float* x     = (const float*)d_in[0];
  const float* bn0_g = (const float*)d_in[1];
  const float* bn0_b = (const float*)d_in[2];
  const float* bn0_m = (const float*)d_in[3];
  const float* bn0_v = (const float*)d_in[4];
  const float* shW   = (const float*)d_in[5];
  const float* sh_g  = (const float*)d_in[6];
  const float* sh_b  = (const float*)d_in[7];
  const float* sh_m  = (const float*)d_in[8];
  const float* sh_v  = (const float*)d_in[9];
  const float* stW   = (const float*)d_in[10];
  const float* st_g  = (const float*)d_in[11];
  const float* st_b  = (const float*)d_in[12];
  const float* st_m  = (const float*)d_in[13];
  const float* st_v  = (const float*)d_in[14];
  // d_in[15..19] = atW, at_g, at_b, at_m, at_v : dead code (never feeds output)
  const float* fW    = (const float*)d_in[20];
  const float* fb    = (const float*)d_in[21];

  unsigned short* wsu = (unsigned short*)d_ws;
  float* wsf = (float*)d_ws;

  prep_w<<<88, 256, 0, stream>>>(shW, stW, bn0_g, bn0_v, wsu);
  prep_b<<<256, 256, 0, stream>>>(shW, bn0_g, bn0_b, bn0_m, bn0_v, sh_g, sh_b, sh_m,
                                  sh_v, st_g, st_b, st_m, st_v, wsf);
  tabnet_main<<<2048, 256, 0, stream>>>(x, wsu, wsf, fW, fb, (float*)d_out);
}